// Round 17
// baseline (85.636 us; speedup 1.0000x reference)
//
#include <hip/hip_runtime.h>

typedef __attribute__((ext_vector_type(8))) short short8;
typedef __attribute__((ext_vector_type(4))) float f32x4;
typedef __attribute__((ext_vector_type(4))) unsigned short us4;

constexpr int NB = 8, NC = 256, IH = 64, IW = 96;
constexpr int PATCH = 21, RAD = 10;
constexpr int TI = 8, TJ = 8;            // pixel tile
constexpr int WIN = 28, NWIN = 784;      // x2 window per tile
constexpr int KC = 32, NKS = NC / KC;    // channel chunking
constexpr int PLANE = IH * IW;
constexpr int PH = IH + 2 * RAD, PW = IW + 2 * RAD;   // 84 x 116 padded x2
constexpr int WCH = 448;                 // wave-private B chunks per K-step (112 pos x 4)
constexpr int WBUF = 8 * WCH;            // 3584 chunks per buffer (8 waves)
constexpr int ASTR = IH * IW * KC;       // per-ks stride in x1k (elements)
constexpr int BSTR = PH * PW * KC;       // per-ks stride in x2k (elements)
constexpr size_t X1T_ELEMS = (size_t)NB * NKS * ASTR;   // 12.58M
constexpr size_t X2P_ELEMS = (size_t)NB * NKS * BSTR;   // 19.96M
constexpr int GSTR = 65;                 // G-chunk m-stride (floats)
constexpr int X1BLKS = NB * IH * 8;      // 4096 prepass blocks for x1
constexpr int X2BLKS = NB * PH * 8;      // 5376 prepass blocks for x2

__device__ __forceinline__ unsigned short f2bf(float f) {
  unsigned u = __builtin_bit_cast(unsigned, f);
  u += 0x7fffu + ((u >> 16) & 1u);       // RNE
  return (unsigned short)(u >> 16);
}

// ---- merged pre-pass (R16-validated, BW-bound): NCHW fp32 -> K-major bf16 ----
__global__ __launch_bounds__(256) void prepass_kmajor(
    const float* __restrict__ x1, const float* __restrict__ x2,
    unsigned short* __restrict__ x1k, unsigned short* __restrict__ x2k) {
  __shared__ float lsf[32 * 97];
  const int t = threadIdx.x;
  if (blockIdx.x < X1BLKS) {
    const int blk = blockIdx.x;          // b*512 + i*8 + ct
    const int ct = blk & 7, i = (blk >> 3) & 63, b = blk >> 9;
    const int c0 = ct * 32;
    const float* sp = x1 + ((size_t)b * NC + c0) * PLANE + (size_t)i * IW;
#pragma unroll
    for (int k = 0; k < 3; ++k) {        // 768 float4
      int idx = k * 256 + t;
      int c = idx / 24, j4 = idx - c * 24;
      f32x4 v = *(const f32x4*)(sp + (size_t)c * PLANE + 4 * j4);
      float* lp = &lsf[c * 97 + 4 * j4];
      lp[0] = v[0]; lp[1] = v[1]; lp[2] = v[2]; lp[3] = v[3];
    }
    __syncthreads();
    unsigned short* dp = x1k + (((size_t)(b * NKS + ct) * IH + i) * IW) * KC;
#pragma unroll
    for (int k = 0; k < 3; ++k) {
      int o = k * 256 + t;
      int j = o >> 3, cq = o & 7;
      us4 v = {f2bf(lsf[(cq * 4 + 0) * 97 + j]), f2bf(lsf[(cq * 4 + 1) * 97 + j]),
               f2bf(lsf[(cq * 4 + 2) * 97 + j]), f2bf(lsf[(cq * 4 + 3) * 97 + j])};
      *(us4*)&dp[(size_t)j * KC + cq * 4] = v;
    }
  } else {
    const int blk = blockIdx.x - X1BLKS; // b*(84*8) + i*8 + ct
    const int ct = blk & 7, i = (blk >> 3) % PH, b = blk / (PH * 8);
    const int c0 = ct * 32;
    const int isrc = i - RAD;
    const bool rowok = (unsigned)isrc < (unsigned)IH;
    if (rowok) {
      const float* sp = x2 + ((size_t)b * NC + c0) * PLANE + (size_t)isrc * IW;
#pragma unroll
      for (int k = 0; k < 3; ++k) {
        int idx = k * 256 + t;
        int c = idx / 24, j4 = idx - c * 24;
        f32x4 v = *(const f32x4*)(sp + (size_t)c * PLANE + 4 * j4);
        float* lp = &lsf[c * 97 + 4 * j4];
        lp[0] = v[0]; lp[1] = v[1]; lp[2] = v[2]; lp[3] = v[3];
      }
    }
    __syncthreads();
    unsigned short* dp = x2k + (((size_t)(b * NKS + ct) * PH + i) * PW) * KC;
#pragma unroll
    for (int k = 0; k < 4; ++k) {
      int o = k * 256 + t;
      if (o < PW * 8) {
        int j = o >> 3, cq = o & 7;
        int jsrc = j - RAD;
        us4 v = {0, 0, 0, 0};
        if (rowok && (unsigned)jsrc < (unsigned)IW)
          v = us4{f2bf(lsf[(cq * 4 + 0) * 97 + jsrc]), f2bf(lsf[(cq * 4 + 1) * 97 + jsrc]),
                  f2bf(lsf[(cq * 4 + 2) * 97 + jsrc]), f2bf(lsf[(cq * 4 + 3) * 97 + jsrc])};
        *(us4*)&dp[(size_t)j * KC + cq * 4] = v;
      }
    }
  }
}

// ---- main: 8 wave-autonomous pipelines, NO K-loop barriers ----
// Each wave stages its own 7 col-tiles (448 chunks) into a PRIVATE LDS region
// (double-buffered) via gload_lds and loads its A-frags direct to VGPRs.
// All K-loop hazards are per-wave (program order + counted vmcnt); the only
// cross-wave sync is the epilogue __syncthreads (R15-validated epilogue).
__global__ __launch_bounds__(512, 2) void corr_wavepipe(
    const unsigned short* __restrict__ x1k, const unsigned short* __restrict__ x2k,
    float* __restrict__ out) {
  __shared__ __attribute__((aligned(16))) unsigned short ls[2 * WBUF * 8];  // 114688 B

  const int t = threadIdx.x, lane = t & 63, wv = t >> 6;   // wv 0..7
  const int bid = blockIdx.x;
  const int b = bid & 7;                 // batch -> XCD locality
  const int tile = bid >> 3;
  const int ti = tile / 12, tj = tile - ti * 12;
  const int i0 = ti * TI, j0 = tj * TJ;
  const int cbeg = 6 * wv;               // 7 col-tiles/wave; overlaps duplicated privately
  const int qk = lane >> 4, lr = lane & 15;

  const unsigned short* x1b = x1k + (size_t)b * NKS * ASTR;
  const unsigned short* x2b = x2k + (size_t)b * NKS * BSTR;

  // per-wave B sources: local chunk c = s*64 + lane, validated inverse of
  // slot(w,c4) = (4w+c4)^(w&7); global position n = 96*wv + w.
  const unsigned short* srcp[7];
#pragma unroll
  for (int s = 0; s < 7; ++s) {
    int c = s * 64 + lane;
    int w = ((c >> 3) << 1) | (((c >> 2) ^ (c >> 4)) & 1);
    int c4 = (c & 3) ^ (w & 3);
    int n = 96 * wv + w;
    int wi = n / WIN, wj = n - wi * WIN;
    srcp[s] = x2b + ((size_t)(i0 + wi) * PW + (j0 + wj)) * KC + c4 * 8;
  }
  // per-lane A-frag base (R9-validated addressing): frag a = pixels 16a+lr
  const unsigned short* srcA =
      x1b + ((size_t)(i0 + (lr >> 3)) * IW + (j0 + (lr & 7))) * KC + qk * 8;
  constexpr size_t AOFF = (size_t)2 * IW * KC;

  f32x4 acc[4][7];
#pragma unroll
  for (int a = 0; a < 4; ++a)
#pragma unroll
    for (int cc = 0; cc < 7; ++cc) acc[a][cc] = (f32x4){0.f, 0.f, 0.f, 0.f};

  short8 aA0, aA1, aA2, aA3, aB0, aB1, aB2, aB3;   // two A reg sets (ping-pong)

#define ALOAD(S, KS)                                                                \
  {                                                                                 \
    const unsigned short* ap = srcA + (size_t)(KS) * ASTR;                          \
    a##S##0 = *(const short8*)(ap);                                                 \
    a##S##1 = *(const short8*)(ap + AOFF);                                          \
    a##S##2 = *(const short8*)(ap + 2 * AOFF);                                      \
    a##S##3 = *(const short8*)(ap + 3 * AOFF);                                      \
  }

#define STAGEW(BUF, KS)                                                             \
  {                                                                                 \
    unsigned short* lb = &ls[((BUF) * WBUF + wv * WCH) * 8];                        \
    _Pragma("unroll")                                                               \
    for (int s = 0; s < 7; ++s)                                                     \
      __builtin_amdgcn_global_load_lds(                                             \
          (const void*)(srcp[s] + (size_t)(KS) * BSTR),                             \
          (void*)(lb + s * 512), 16, 0, 0);                                         \
  }

#define COMPUTE(BUF, S)                                                             \
  {                                                                                 \
    const unsigned short* lb = &ls[((BUF) * WBUF + wv * WCH) * 8];                  \
    _Pragma("unroll")                                                               \
    for (int cc = 0; cc < 7; ++cc) {                                                \
      int wl = 16 * cc + lr;                                                        \
      int slot = (4 * wl + qk) ^ (lr & 7);                                          \
      short8 bf = *(const short8*)(lb + slot * 8);                                  \
      acc[0][cc] = __builtin_amdgcn_mfma_f32_16x16x32_bf16(a##S##0, bf, acc[0][cc], 0, 0, 0); \
      acc[1][cc] = __builtin_amdgcn_mfma_f32_16x16x32_bf16(a##S##1, bf, acc[1][cc], 0, 0, 0); \
      acc[2][cc] = __builtin_amdgcn_mfma_f32_16x16x32_bf16(a##S##2, bf, acc[2][cc], 0, 0, 0); \
      acc[3][cc] = __builtin_amdgcn_mfma_f32_16x16x32_bf16(a##S##3, bf, acc[3][cc], 0, 0, 0); \
    }                                                                               \
  }

  // prologue: {A(0), S(0)} | fence | {A(1), S(1)}  (fence pins group boundary
  // so "leave newest 11" at iter 0 is exactly A(1)+S(1))
  ALOAD(A, 0)
  STAGEW(0, 0)
  asm volatile("" ::: "memory");
  ALOAD(B, 1)
  STAGEW(1, 1)

  // iter ks: issue {A(ks+1), S(ks+1)->buf[(ks+1)&1]} (one group; WAR on that
  // buffer is self-ordered: this wave read it at iter ks-1, program order);
  // vmcnt leaves newest 11 = A(ks+1)+S(ks+1) -> drains S(ks)+A(ks); compute.
  // The vmcnt asm ("memory") is itself the inter-group fence.
#define ITER(KS, SL, SC, VM)                                                        \
  if ((KS) >= 1 && (KS) < 7) { ALOAD(SL, (KS) + 1) STAGEW(((KS) + 1) & 1, (KS) + 1) } \
  asm volatile("s_waitcnt vmcnt(" #VM ")" ::: "memory");                            \
  COMPUTE((KS) & 1, SC)

  ITER(0, A, A, 11)
  ITER(1, A, B, 11)
  ITER(2, B, A, 11)
  ITER(3, A, B, 11)
  ITER(4, B, A, 11)
  ITER(5, A, B, 11)
  ITER(6, B, A, 11)
  ITER(7, A, B, 0)
#undef ITER
#undef COMPUTE
#undef STAGEW
#undef ALOAD

  // ---- epilogue: LDS diagonal transpose -> coalesced 32B stores (R15, verbatim) ----
  float* gf = (float*)ls;
#pragma unroll
  for (int ch = 0; ch < 2; ++ch) {
    __syncthreads();                     // all waves' K-loops done; reads drained
    const int n0 = ch ? 384 : 0;
#pragma unroll
    for (int a = 0; a < 4; ++a)
#pragma unroll
      for (int cc = 0; cc < 7; ++cc) {
        int ccg = cbeg + cc;
        if (ch ? (ccg >= 24) : (ccg <= 24)) {
          int nl = 16 * ccg + lr - n0;
          int mb = 16 * a + 4 * qk;
          float* gp = &gf[nl * GSTR + mb];
          gp[0] = acc[a][cc][0]; gp[1] = acc[a][cc][1];
          gp[2] = acc[a][cc][2]; gp[3] = acc[a][cc][3];
        }
      }
    __syncthreads();
    for (int s = t; s < 1764; s += 512) {
      int pidx = s / 21, pj = s - pidx * 21;
      int ii = 0, rem = pidx, stop = 0;
#pragma unroll
      for (int k = 0; k < 7; ++k) {
        int cnt = ch ? (7 + k) : (14 - k);
        int go = (!stop) && (rem >= cnt);
        rem -= go ? cnt : 0;
        ii += go;
        stop |= !go;
      }
      int pi = ch ? (14 - ii + rem) : rem;
      int nl = 28 * (pi + ii) + pj - n0;
      int ms = 8 * ii;
      float g[8];
#pragma unroll
      for (int e = 0; e < 8; ++e) g[e] = gf[(nl + e) * GSTR + ms + e];
      float* op = out + ((((size_t)b * PATCH + pi) * PATCH + pj) * IH + (i0 + ii)) * IW + j0;
      f32x4 v0 = {g[0], g[1], g[2], g[3]};
      f32x4 v1 = {g[4], g[5], g[6], g[7]};
      *(f32x4*)op = v0;
      *(f32x4*)(op + 4) = v1;
    }
  }
}

// ---------------- fallback (R1, validated): NCHW fp32 in-kernel ----------------
constexpr int LDKF = 40;
__global__ __launch_bounds__(512, 2) void corr_mfma_fb(
    const float* __restrict__ x1, const float* __restrict__ x2, float* __restrict__ out) {
  __shared__ __attribute__((aligned(16))) unsigned short lsA[64 * LDKF];
  __shared__ __attribute__((aligned(16))) unsigned short lsB[NWIN * LDKF];
  const int t = threadIdx.x;
  const int b = blockIdx.y;
  const int ti = blockIdx.x / 12, tj = blockIdx.x % 12;
  const int i0 = ti * TI, j0 = tj * TJ;
  const int lane = t & 63, wv = t >> 6;
  const int mtp = wv >> 2, cg = wv & 3, cbeg = cg * 12;
  const int qk = lane >> 4, lr = lane & 15;
  f32x4 acc[2][13];
#pragma unroll
  for (int a = 0; a < 2; ++a)
#pragma unroll
    for (int cc = 0; cc < 13; ++cc) acc[a][cc] = (f32x4){0.f, 0.f, 0.f, 0.f};
  const int am = t & 63, ak4 = t >> 6;
  const int aii = am >> 3, ajj = am & 7;
  const float* x1p = x1 + ((size_t)b * NC + 4 * ak4) * PLANE + (size_t)(i0 + aii) * IW + (j0 + ajj);
  const float* x2b = x2 + (size_t)b * NC * PLANE;
  for (int ks = 0; ks < NKS; ++ks) {
    __syncthreads();
    {
      const float* p = x1p + (size_t)ks * KC * PLANE;
      us4 v = {f2bf(p[0]), f2bf(p[PLANE]), f2bf(p[2 * PLANE]), f2bf(p[3 * PLANE])};
      *(us4*)&lsA[am * LDKF + 4 * ak4] = v;
    }
    for (int w = t; w < NWIN; w += 512) {
      const int wi = w / WIN, wj = w - wi * WIN;
      const int gi = i0 - RAD + wi, gj = j0 - RAD + wj;
      const bool ok = ((unsigned)gi < (unsigned)IH) && ((unsigned)gj < (unsigned)IW);
      const float* p = x2b + ((size_t)(ks * KC) * IH + gi) * IW + gj;
      unsigned short* dst = &lsB[w * LDKF];
#pragma unroll
      for (int k4 = 0; k4 < 8; ++k4) {
        const float* q = p + (size_t)(4 * k4) * PLANE;
        us4 v = {f2bf(ok ? q[0] : 0.f), f2bf(ok ? q[PLANE] : 0.f),
                 f2bf(ok ? q[2 * PLANE] : 0.f), f2bf(ok ? q[3 * PLANE] : 0.f)};
        *(us4*)&dst[4 * k4] = v;
      }
    }
    __syncthreads();
    short8 a0 = *(const short8*)&lsA[(32 * mtp + lr) * LDKF + 8 * qk];
    short8 a1 = *(const short8*)&lsA[(32 * mtp + 16 + lr) * LDKF + 8 * qk];
#pragma unroll
    for (int cc = 0; cc < 13; ++cc) {
      const int wrow = 16 * (cbeg + cc) + lr;
      short8 bf = *(const short8*)&lsB[wrow * LDKF + 8 * qk];
      acc[0][cc] = __builtin_amdgcn_mfma_f32_16x16x32_bf16(a0, bf, acc[0][cc], 0, 0, 0);
      acc[1][cc] = __builtin_amdgcn_mfma_f32_16x16x32_bf16(a1, bf, acc[1][cc], 0, 0, 0);
    }
  }
#pragma unroll
  for (int a = 0; a < 2; ++a) {
    const int mb = 16 * (2 * mtp + a) + qk * 4;
#pragma unroll
    for (int cc = 0; cc < 13; ++cc) {
      if (cg > 0 && cc == 0) continue;
      const int n = 16 * (cbeg + cc) + lr;
      const int wi = n / WIN, wj = n - wi * WIN;
#pragma unroll
      for (int r = 0; r < 4; ++r) {
        const int m = mb + r;
        const int ii = m >> 3, jj = m & 7;
        const int pi = wi - ii, pj = wj - jj;
        if ((unsigned)pi < (unsigned)PATCH && (unsigned)pj < (unsigned)PATCH)
          out[((((size_t)b * PATCH + pi) * PATCH + pj) * IH + (i0 + ii)) * IW + (j0 + jj)] =
              acc[a][cc][r];
      }
    }
  }
}

extern "C" void kernel_launch(void* const* d_in, const int* in_sizes, int n_in,
                              void* d_out, int out_size, void* d_ws, size_t ws_size,
                              hipStream_t stream) {
  const float* x1 = (const float*)d_in[0];
  const float* x2 = (const float*)d_in[1];
  float* out = (float*)d_out;
  const size_t need = (X1T_ELEMS + X2P_ELEMS) * sizeof(unsigned short);  // ~65.1 MB
  if (ws_size >= need) {
    unsigned short* x1k = (unsigned short*)d_ws;
    unsigned short* x2k = x1k + X1T_ELEMS;
    prepass_kmajor<<<X1BLKS + X2BLKS, 256, 0, stream>>>(x1, x2, x1k, x2k);
    corr_wavepipe<<<NB * 96, 512, 0, stream>>>(x1k, x2k, out);
  } else {
    dim3 grid(96, NB);
    corr_mfma_fb<<<grid, 512, 0, stream>>>(x1, x2, out);
  }
}